// Round 5
// baseline (865.950 us; speedup 1.0000x reference)
//
#include <hip/hip_runtime.h>
#include <hip/hip_bf16.h>

typedef __attribute__((ext_vector_type(8))) short bf16x8;
typedef __attribute__((ext_vector_type(4))) float f32x4;

#define N_OUT 65536
#define CIN   256
#define COUT  512
#define BM    64
#define BK    32
#define NKS   64    // 2048 / 32 K-steps

__device__ __forceinline__ unsigned short f2bf(float f) {
  union { __hip_bfloat16 h; unsigned short u; } c;
  c.h = __float2bfloat16(f);
  return c.u;
}

__device__ __forceinline__ bf16x8 pack8(f32x4 a, f32x4 b) {
  unsigned short u[8];
  u[0] = f2bf(a.x); u[1] = f2bf(a.y); u[2] = f2bf(a.z); u[3] = f2bf(a.w);
  u[4] = f2bf(b.x); u[5] = f2bf(b.y); u[6] = f2bf(b.z); u[7] = f2bf(b.w);
  return *reinterpret_cast<bf16x8*>(u);
}

__device__ __forceinline__ void gload_lds16f(const float* g, float* l) {
  __builtin_amdgcn_global_load_lds(
      (const __attribute__((address_space(1))) void*)g,
      (__attribute__((address_space(3))) void*)l, 16, 0, 0);
}
__device__ __forceinline__ void gload_lds16u(const unsigned short* g, unsigned short* l) {
  __builtin_amdgcn_global_load_lds(
      (const __attribute__((address_space(1))) void*)g,
      (__attribute__((address_space(3))) void*)l, 16, 0, 0);
}

// --- weight prep: W[k][n] f32 -> Wt bf16 tiled [kb][slot][n][w]:
//     Wt[kb*16384 + s*4096 + n*8 + w] = bf16(W[(kb*32 + s*8 + w)*512 + n])
__global__ void wprep_kernel(const float* __restrict__ W, unsigned short* __restrict__ Wt) {
  int idx = blockIdx.x * blockDim.x + threadIdx.x;
  if (idx >= 64 * 4 * COUT) return;
  int n  = idx & (COUT - 1);
  int s  = (idx >> 9) & 3;
  int kb = idx >> 11;
  unsigned short tmp[8];
#pragma unroll
  for (int w = 0; w < 8; ++w)
    tmp[w] = f2bf(W[(size_t)(kb * 32 + s * 8 + w) * COUT + n]);
  *reinterpret_cast<bf16x8*>(Wt + ((size_t)kb * 16384 + s * 4096 + n * 8)) =
      *reinterpret_cast<bf16x8*>(tmp);
}

// --- main GEMM: 64-row blocks, 4 waves, 2 blocks/CU (LDS=80KB exactly)
__global__ __launch_bounds__(256, 2) void gemm_kernel(
    const float* __restrict__ data,
    const int*   __restrict__ neigh,
    const unsigned short* __restrict__ Wt,
    float* __restrict__ out,
    float* __restrict__ psum,
    float* __restrict__ psq)
{
  __shared__ union {
    struct {
      float          a[2][BM * BK];     // 2 x 8 KB, 16B chunks XOR-swizzled
      unsigned short b[2][BK * COUT];   // 2 x 32 KB, linear (layout conflict-free)
    } r;                                 // = 80 KB
    float st[4][COUT];                   // stats overlay (after all DMA retired)
  } sm;

  const int tid = threadIdx.x;
  const int l   = tid & 63;
  const int w   = tid >> 6;      // 4 waves
  const int wr  = w >> 1;        // 0..1 (32-row strip)
  const int wc  = w & 1;         // 0..1 (256-col strip)
  const int lg  = l >> 4;
  const int lm  = l & 15;

  // bijective XCD swizzle (1024 % 8 == 0): XCD x gets contiguous row-range
  const int bid = blockIdx.x;
  const int m0  = ((bid & 7) * 128 + (bid >> 3)) * BM;

  // lane's two staged rows (q=0,1): r0, r0+8
  const int r0 = w * 16 + (l >> 3);

  f32x4 acc[2][16];
#pragma unroll
  for (int i = 0; i < 2; ++i)
#pragma unroll
    for (int j = 0; j < 16; ++j) acc[i][j] = (f32x4){0.f, 0.f, 0.f, 0.f};

  bf16x8 af[2];

  // A: 2 DMA/wave/step. op q: 8 rows (lane l -> row base+(l>>3), slot l&7,
  // global source supplies logical chunk (l&7)^((l>>3)&7)  [rule 21].
#define AISSUE(k0_, buf_, o0_, o1_) do { \
    gload_lds16f(data + (o0_) + (k0_) + (((l & 7) ^ ((l >> 3) & 7)) << 2), \
                 &sm.r.a[buf_][(w * 16) * BK]); \
    gload_lds16f(data + (o1_) + (k0_) + (((l & 7) ^ ((l >> 3) & 7)) << 2), \
                 &sm.r.a[buf_][(w * 16 + 8) * BK]); \
  } while (0)

  // B: 8 DMA/wave/step, fully linear (panel contiguous 32 KB)
#define BISSUE(kb_, buf_) do { \
    const unsigned short* bs_ = Wt + (size_t)(kb_) * 16384; \
    _Pragma("unroll") \
    for (int p_ = 0; p_ < 8; ++p_) \
      gload_lds16u(bs_ + (w * 8 + p_) * 512 + l * 8, \
                   &sm.r.b[buf_][(w * 8 + p_) * 512]); \
  } while (0)

#define COMPUTE(buf_) do { \
    _Pragma("unroll") \
    for (int mi_ = 0; mi_ < 2; ++mi_) { \
      int R_ = wr * 32 + mi_ * 16 + lm; \
      const f32x4* b_ = reinterpret_cast<const f32x4*>(&sm.r.a[buf_][R_ * BK]); \
      f32x4 x0_ = b_[(2 * lg)     ^ (R_ & 7)]; \
      f32x4 x1_ = b_[(2 * lg + 1) ^ (R_ & 7)]; \
      af[mi_] = pack8(x0_, x1_); \
    } \
    __builtin_amdgcn_s_setprio(1); \
    _Pragma("unroll") \
    for (int ni_ = 0; ni_ < 16; ++ni_) { \
      bf16x8 bfr_ = *reinterpret_cast<const bf16x8*>( \
          &sm.r.b[buf_][lg * 4096 + (wc * 256 + ni_ * 16 + lm) * 8]); \
      acc[0][ni_] = __builtin_amdgcn_mfma_f32_16x16x32_bf16(af[0], bfr_, acc[0][ni_], 0, 0, 0); \
      acc[1][ni_] = __builtin_amdgcn_mfma_f32_16x16x32_bf16(af[1], bfr_, acc[1][ni_], 0, 0, 0); \
    } \
    __builtin_amdgcn_s_setprio(0); \
  } while (0)

  // ---- prologue: child-0 offsets; steps 0,1 in flight
  unsigned offA0 = ((unsigned)neigh[(m0 + r0) * 8])     << 8;
  unsigned offA1 = ((unsigned)neigh[(m0 + r0 + 8) * 8]) << 8;
  AISSUE(0,  0, offA0, offA1); BISSUE(0, 0);
  AISSUE(32, 1, offA0, offA1); BISSUE(1, 1);

  // ---- main loop: outer child cn (dynamic), inner 8 k-steps (unrolled)
#pragma unroll 1
  for (int cn = 0; cn < 8; ++cn) {
    const int cnn = (cn < 7) ? cn + 1 : 7;
    unsigned offB0 = ((unsigned)neigh[(m0 + r0) * 8 + cnn])     << 8;
    unsigned offB1 = ((unsigned)neigh[(m0 + r0 + 8) * 8 + cnn]) << 8;
#pragma unroll
    for (int j = 0; j < 8; ++j) {
      // wait: own step-t DMA (issued 2 iters ago) retired; 10 newer stay in flight
      if (j == 7) {
        if (cn == 7) asm volatile("s_waitcnt vmcnt(0)" ::: "memory");
        else         asm volatile("s_waitcnt vmcnt(10)" ::: "memory");
      } else {
        asm volatile("s_waitcnt vmcnt(10)" ::: "memory");
      }
      __builtin_amdgcn_s_barrier();
      asm volatile("" ::: "memory");      // no LDS-read hoist above barrier
      COMPUTE(j & 1);
      asm volatile("" ::: "memory");      // no LDS-read sink below barrier
      __builtin_amdgcn_s_barrier();
      // issue step t+2 into the just-freed buffer
      if (j < 6) {
        AISSUE(((j + 2) & 7) * BK, j & 1, offA0, offA1);
        BISSUE(cn * 8 + j + 2, j & 1);
      } else if (cn < 7) {
        AISSUE(((j + 2) & 7) * BK, j & 1, offB0, offB1);
        BISSUE(cn * 8 + j + 2, j & 1);
      }
    }
    offA0 = offB0; offA1 = offB1;
  }

  // ---- epilogue 1: raw out (C layout: col = lane&15, row = (lane>>4)*4 + reg)
#pragma unroll
  for (int mi = 0; mi < 2; ++mi) {
#pragma unroll
    for (int r = 0; r < 4; ++r) {
      size_t row = (size_t)(m0 + wr * 32 + mi * 16 + lg * 4 + r);
      float* op = out + row * COUT + wc * 256 + lm;
#pragma unroll
      for (int ni = 0; ni < 16; ++ni) op[ni * 16] = acc[mi][ni][r];
    }
  }

  // ---- epilogue 2: deterministic per-block column sums/sumsq
  __syncthreads();   // all DMA retired (vmcnt(0) above) + LDS reads done
#pragma unroll
  for (int ni = 0; ni < 16; ++ni) {
    float s1 = 0.f, s2 = 0.f;
#pragma unroll
    for (int mi = 0; mi < 2; ++mi)
#pragma unroll
      for (int r = 0; r < 4; ++r) { float v = acc[mi][ni][r]; s1 += v; s2 += v * v; }
    s1 += __shfl_xor(s1, 16, 64); s1 += __shfl_xor(s1, 32, 64);
    s2 += __shfl_xor(s2, 16, 64); s2 += __shfl_xor(s2, 32, 64);
    if (l < 16) {
      sm.st[wr][wc * 256 + ni * 16 + l]     = s1;
      sm.st[2 + wr][wc * 256 + ni * 16 + l] = s2;
    }
  }
  __syncthreads();
#pragma unroll
  for (int h = 0; h < 2; ++h) {
    int c = h * 256 + tid;
    psum[(size_t)blockIdx.x * COUT + c] = sm.st[0][c] + sm.st[1][c];
    psq [(size_t)blockIdx.x * COUT + c] = sm.st[2][c] + sm.st[3][c];
  }
#undef AISSUE
#undef BISSUE
#undef COMPUTE
}

// --- stats reduction, stage 1: 1024 -> 64 partials per column
__global__ void reduce1_kernel(const float* __restrict__ psum, const float* __restrict__ psq,
                               float* __restrict__ p2) {
  int c = threadIdx.x, b = blockIdx.x;
  float s = 0.f, q = 0.f;
#pragma unroll
  for (int j = 0; j < 16; ++j) {
    s += psum[(size_t)(b * 16 + j) * COUT + c];
    q += psq [(size_t)(b * 16 + j) * COUT + c];
  }
  p2[b * 1024 + c] = s;
  p2[b * 1024 + 512 + c] = q;
}

// --- stats reduction, stage 2: mean/var -> per-column scale/shift
__global__ void reduce2_kernel(const float* __restrict__ p2,
                               const float* __restrict__ gamma,
                               const float* __restrict__ beta,
                               float* __restrict__ scsh) {
  int c = threadIdx.x;
  float s = 0.f, q = 0.f;
  for (int b = 0; b < 64; ++b) { s += p2[b * 1024 + c]; q += p2[b * 1024 + 512 + c]; }
  float mean = s * (1.f / 65536.f);
  float var  = q * (1.f / 65536.f) - mean * mean;
  float rs   = rsqrtf(var + 1e-5f);
  float sc   = gamma[c] * rs;
  scsh[c] = sc;
  scsh[COUT + c] = beta[c] - mean * sc;   // conv bias cancels in BN
}

// --- apply BN in-place
__global__ void bn_kernel(float* __restrict__ out, const float* __restrict__ scsh) {
  __shared__ float sc[COUT], sh[COUT];
  int t = threadIdx.x;
  sc[t] = scsh[t];
  sh[t] = scsh[COUT + t];
  __syncthreads();
  f32x4* o4 = reinterpret_cast<f32x4*>(out);
  const size_t total  = (size_t)N_OUT * COUT / 4;
  const size_t stride = (size_t)gridDim.x * blockDim.x;
  for (size_t i = (size_t)blockIdx.x * blockDim.x + t; i < total; i += stride) {
    f32x4 v = o4[i];
    int c = ((int)(i & 127)) * 4;
    v.x = v.x * sc[c]     + sh[c];
    v.y = v.y * sc[c + 1] + sh[c + 1];
    v.z = v.z * sc[c + 2] + sh[c + 2];
    v.w = v.w * sc[c + 3] + sh[c + 3];
    o4[i] = v;
  }
}

extern "C" void kernel_launch(void* const* d_in, const int* in_sizes, int n_in,
                              void* d_out, int out_size, void* d_ws, size_t ws_size,
                              hipStream_t stream) {
  const float* data   = (const float*)d_in[0];
  const float* weight = (const float*)d_in[1];
  const float* gamma  = (const float*)d_in[3];
  const float* beta   = (const float*)d_in[4];
  const int*   neigh  = (const int*)d_in[5];
  float* out = (float*)d_out;

  char* ws = (char*)d_ws;
  unsigned short* Wt = (unsigned short*)ws;                        // 2 MB
  float* psum = (float*)(ws + (2u << 20));                         // 2 MB
  float* psq  = (float*)(ws + (4u << 20));                         // 2 MB
  float* p2   = (float*)(ws + (6u << 20));                         // 256 KB
  float* scsh = (float*)(ws + (6u << 20) + (256u << 10));          // 4 KB

  wprep_kernel<<<512, 256, 0, stream>>>(weight, Wt);
  gemm_kernel<<<N_OUT / BM, 256, 0, stream>>>(data, neigh, Wt, out, psum, psq);
  reduce1_kernel<<<64, 512, 0, stream>>>(psum, psq, p2);
  reduce2_kernel<<<1, 512, 0, stream>>>(p2, gamma, beta, scsh);
  bn_kernel<<<2048, 512, 0, stream>>>(out, scsh);
}

// Round 6
// 283.518 us; speedup vs baseline: 3.0543x; 3.0543x over previous
//
#include <hip/hip_runtime.h>
#include <hip/hip_bf16.h>

typedef __attribute__((ext_vector_type(8))) short bf16x8;
typedef __attribute__((ext_vector_type(4))) float f32x4;

#define N_OUT 65536
#define CIN   256
#define COUT  512
#define BM    128
#define BN    256
#define BK    32
#define NKS   64    // 2048 / 32 K-steps

__device__ __forceinline__ unsigned short f2bf(float f) {
  union { __hip_bfloat16 h; unsigned short u; } c;
  c.h = __float2bfloat16(f);
  return c.u;
}

__device__ __forceinline__ bf16x8 pack8(f32x4 a, f32x4 b) {
  unsigned short u[8];
  u[0] = f2bf(a.x); u[1] = f2bf(a.y); u[2] = f2bf(a.z); u[3] = f2bf(a.w);
  u[4] = f2bf(b.x); u[5] = f2bf(b.y); u[6] = f2bf(b.z); u[7] = f2bf(b.w);
  return *reinterpret_cast<bf16x8*>(u);
}

__device__ __forceinline__ void gload_lds16f(const float* g, float* l) {
  __builtin_amdgcn_global_load_lds(
      (const __attribute__((address_space(1))) void*)g,
      (__attribute__((address_space(3))) void*)l, 16, 0, 0);
}
__device__ __forceinline__ void gload_lds16u(const unsigned short* g, unsigned short* l) {
  __builtin_amdgcn_global_load_lds(
      (const __attribute__((address_space(1))) void*)g,
      (__attribute__((address_space(3))) void*)l, 16, 0, 0);
}

// --- weight prep: W[k][n] f32 -> Wt bf16 tiled [kb][slot][n][w]:
//     Wt[kb*16384 + s*4096 + n*8 + w] = bf16(W[(kb*32 + s*8 + w)*512 + n])
__global__ void wprep_kernel(const float* __restrict__ W, unsigned short* __restrict__ Wt) {
  int idx = blockIdx.x * blockDim.x + threadIdx.x;
  if (idx >= 64 * 4 * COUT) return;
  int n  = idx & (COUT - 1);
  int s  = (idx >> 9) & 3;
  int kb = idx >> 11;
  unsigned short tmp[8];
#pragma unroll
  for (int w = 0; w < 8; ++w)
    tmp[w] = f2bf(W[(size_t)(kb * 32 + s * 8 + w) * COUT + n]);
  *reinterpret_cast<bf16x8*>(Wt + ((size_t)kb * 16384 + s * 4096 + n * 8)) =
      *reinterpret_cast<bf16x8*>(tmp);
}

// --- main GEMM: 128x256 blocks, 8 waves, wave tile 32x128 (acc=64 regs),
//     all-DMA staging, counted vmcnt, 2 blocks/CU (reg-limited, LDS=52KB)
__global__ __launch_bounds__(512, 4) void gemm_kernel(
    const float* __restrict__ data,
    const int*   __restrict__ neigh,
    const unsigned short* __restrict__ Wt,
    float* __restrict__ out,
    float* __restrict__ psum,
    float* __restrict__ psq)
{
  __shared__ union {
    struct {
      float          a[2][BM * BK];   // 2 x 16 KB, 16B chunks XOR-swizzled
      unsigned short b[2][BK * BN];   // 2 x 16 KB, linear conflict-free
    } r;                              // 48 KB
    float st[8][BN];                  // 8 KB stats overlay (post-loop)
  } sm;
  __shared__ unsigned int offs[BM * 8];   // 4 KB

  const int tid = threadIdx.x;
  const int l   = tid & 63;
  const int w   = tid >> 6;       // 8 waves
  const int wr  = w >> 1;         // 0..3 (32-row strip)
  const int wc  = w & 1;          // 0..1 (128-col strip)
  const int lg  = l >> 4;
  const int lm  = l & 15;

  // bijective XCD swizzle (1024 % 8 == 0); each XCD stays on one B-half
  const int bid = blockIdx.x;
  const int wg  = (bid & 7) * 128 + (bid >> 3);
  const int n0  = (wg >> 9) * BN;       // 0 or 256
  const int m0  = (wg & 511) * BM;

  // neigh -> LDS offset table (float offsets into data)
  for (int e = tid; e < BM * 8; e += 512)
    offs[e] = ((unsigned)neigh[(size_t)m0 * 8 + e]) << 8;
  __syncthreads();

  f32x4 acc[2][8];
#pragma unroll
  for (int i = 0; i < 2; ++i)
#pragma unroll
    for (int j = 0; j < 8; ++j) acc[i][j] = (f32x4){0.f, 0.f, 0.f, 0.f};

  bf16x8 af[2];

  const int lrow = l >> 3;                              // 0..7
  const int ra   = (w * 16 + lrow) * 8;                 // offs index base, op 0
  const int rb   = (w * 16 + 8 + lrow) * 8;             // op 1
  const int swzf = ((l & 7) ^ lrow) << 2;               // swizzled 16B chunk (rule 21)
  const int q0   = w * 2;                               // B chunk pair
  const unsigned short* bbase =
      Wt + n0 * 8 + (q0 >> 2) * 4096 + (q0 & 3) * 512 + l * 8;

  // A: 2 DMA/wave/step (8 rows each; lane l -> row l>>3, LDS slot l&7,
  //    global chunk (l&7)^(l>>3) so that LDS slot s holds chunk s^(row&7))
#define AISSUE(t_, buf_) do { \
    int cn_ = (t_) >> 3; \
    int k0_ = ((t_) & 7) * BK; \
    unsigned o0_ = offs[ra + cn_]; \
    unsigned o1_ = offs[rb + cn_]; \
    gload_lds16f(data + o0_ + k0_ + swzf, &sm.r.a[buf_][(w * 16) * BK]); \
    gload_lds16f(data + o1_ + k0_ + swzf, &sm.r.a[buf_][(w * 16 + 8) * BK]); \
  } while (0)

  // B: 2 DMA/wave/step, linear 512-short chunks
#define BISSUE(t_, buf_) do { \
    const unsigned short* bs_ = bbase + (size_t)(t_) * 16384; \
    gload_lds16u(bs_,       &sm.r.b[buf_][q0 * 512]); \
    gload_lds16u(bs_ + 512, &sm.r.b[buf_][q0 * 512 + 512]); \
  } while (0)

#define COMPUTE(buf_) do { \
    _Pragma("unroll") \
    for (int mi_ = 0; mi_ < 2; ++mi_) { \
      int R_ = wr * 32 + mi_ * 16 + lm; \
      const f32x4* ap_ = reinterpret_cast<const f32x4*>(&sm.r.a[buf_][R_ * BK]); \
      f32x4 x0_ = ap_[(2 * lg)     ^ (R_ & 7)]; \
      f32x4 x1_ = ap_[(2 * lg + 1) ^ (R_ & 7)]; \
      af[mi_] = pack8(x0_, x1_); \
    } \
    _Pragma("unroll") \
    for (int ni_ = 0; ni_ < 8; ++ni_) { \
      bf16x8 bfr_ = *reinterpret_cast<const bf16x8*>( \
          &sm.r.b[buf_][lg * 2048 + (wc * 128 + ni_ * 16 + lm) * 8]); \
      acc[0][ni_] = __builtin_amdgcn_mfma_f32_16x16x32_bf16(af[0], bfr_, acc[0][ni_], 0, 0, 0); \
      acc[1][ni_] = __builtin_amdgcn_mfma_f32_16x16x32_bf16(af[1], bfr_, acc[1][ni_], 0, 0, 0); \
    } \
  } while (0)

  // ---- prologue: steps 0,1 in flight (4 DMA ops/wave each)
  AISSUE(0, 0); BISSUE(0, 0);
  AISSUE(1, 1); BISSUE(1, 1);

#pragma unroll 1
  for (int t = 0; t < NKS; ++t) {
    // counted wait: own 4 step-t ops retired; step t+1's 4 stay in flight
    if (t < NKS - 1) asm volatile("s_waitcnt vmcnt(4)" ::: "memory");
    else             asm volatile("s_waitcnt vmcnt(0)" ::: "memory");
    __builtin_amdgcn_s_barrier();       // all waves: step-t data landed
    asm volatile("" ::: "memory");
    COMPUTE(t & 1);
    asm volatile("" ::: "memory");
    __builtin_amdgcn_s_barrier();       // WAR: reads done before overwrite
    if (t + 2 < NKS) { AISSUE(t + 2, t & 1); BISSUE(t + 2, t & 1); }
  }

  // ---- epilogue 1: raw out (C layout: col = lane&15, row = (lane>>4)*4 + reg)
#pragma unroll
  for (int mi = 0; mi < 2; ++mi) {
#pragma unroll
    for (int r = 0; r < 4; ++r) {
      size_t row = (size_t)(m0 + wr * 32 + mi * 16 + lg * 4 + r);
      float* op = out + row * COUT + n0 + wc * 128 + lm;
#pragma unroll
      for (int ni = 0; ni < 8; ++ni) op[ni * 16] = acc[mi][ni][r];
    }
  }

  // ---- epilogue 2: deterministic per-block column sums/sumsq
  __syncthreads();   // all DMA retired (vmcnt(0)) + LDS reads done
#pragma unroll
  for (int ni = 0; ni < 8; ++ni) {
    float s1 = 0.f, s2 = 0.f;
#pragma unroll
    for (int mi = 0; mi < 2; ++mi)
#pragma unroll
      for (int r = 0; r < 4; ++r) { float v = acc[mi][ni][r]; s1 += v; s2 += v * v; }
    s1 += __shfl_xor(s1, 16, 64); s1 += __shfl_xor(s1, 32, 64);
    s2 += __shfl_xor(s2, 16, 64); s2 += __shfl_xor(s2, 32, 64);
    if (l < 16) {
      sm.st[wr][wc * 128 + ni * 16 + l]     = s1;
      sm.st[4 + wr][wc * 128 + ni * 16 + l] = s2;
    }
  }
  __syncthreads();
  if (tid < 256) {
    float S = sm.st[0][tid] + sm.st[1][tid] + sm.st[2][tid] + sm.st[3][tid];
    psum[(size_t)wg * BN + tid] = S;
  } else {
    int c = tid - 256;
    float Q = sm.st[4][c] + sm.st[5][c] + sm.st[6][c] + sm.st[7][c];
    psq[(size_t)wg * BN + c] = Q;
  }
#undef AISSUE
#undef BISSUE
#undef COMPUTE
}

// --- stats reduction, stage 1: 1024 half-width partials -> 64 per column
__global__ void reduce1_kernel(const float* __restrict__ psum, const float* __restrict__ psq,
                               float* __restrict__ p2) {
  int c = threadIdx.x, b = blockIdx.x;
  int h = c >> 8, crel = c & 255;     // global col c = h*256 + crel; wg = h*512 + mrow
  float s = 0.f, q = 0.f;
#pragma unroll
  for (int j = 0; j < 8; ++j) {
    size_t wgi = (size_t)(h * 512 + b * 8 + j);
    s += psum[wgi * 256 + crel];
    q += psq [wgi * 256 + crel];
  }
  p2[b * 1024 + c] = s;
  p2[b * 1024 + 512 + c] = q;
}

// --- stats reduction, stage 2: mean/var -> per-column scale/shift
__global__ void reduce2_kernel(const float* __restrict__ p2,
                               const float* __restrict__ gamma,
                               const float* __restrict__ beta,
                               float* __restrict__ scsh) {
  int c = threadIdx.x;
  float s = 0.f, q = 0.f;
  for (int b = 0; b < 64; ++b) { s += p2[b * 1024 + c]; q += p2[b * 1024 + 512 + c]; }
  float mean = s * (1.f / 65536.f);
  float var  = q * (1.f / 65536.f) - mean * mean;
  float rs   = rsqrtf(var + 1e-5f);
  float sc   = gamma[c] * rs;
  scsh[c] = sc;
  scsh[COUT + c] = beta[c] - mean * sc;   // conv bias cancels in BN
}

// --- apply BN in-place
__global__ void bn_kernel(float* __restrict__ out, const float* __restrict__ scsh) {
  __shared__ float sc[COUT], sh[COUT];
  int t = threadIdx.x;
  sc[t] = scsh[t];
  sh[t] = scsh[COUT + t];
  __syncthreads();
  f32x4* o4 = reinterpret_cast<f32x4*>(out);
  const size_t total  = (size_t)N_OUT * COUT / 4;
  const size_t stride = (size_t)gridDim.x * blockDim.x;
  for (size_t i = (size_t)blockIdx.x * blockDim.x + t; i < total; i += stride) {
    f32x4 v = o4[i];
    int c = ((int)(i & 127)) * 4;
    v.x = v.x * sc[c]     + sh[c];
    v.y = v.y * sc[c + 1] + sh[c + 1];
    v.z = v.z * sc[c + 2] + sh[c + 2];
    v.w = v.w * sc[c + 3] + sh[c + 3];
    o4[i] = v;
  }
}

extern "C" void kernel_launch(void* const* d_in, const int* in_sizes, int n_in,
                              void* d_out, int out_size, void* d_ws, size_t ws_size,
                              hipStream_t stream) {
  const float* data   = (const float*)d_in[0];
  const float* weight = (const float*)d_in[1];
  const float* gamma  = (const float*)d_in[3];
  const float* beta   = (const float*)d_in[4];
  const int*   neigh  = (const int*)d_in[5];
  float* out = (float*)d_out;

  char* ws = (char*)d_ws;
  unsigned short* Wt = (unsigned short*)ws;                        // 2 MB
  float* psum = (float*)(ws + (2u << 20));                         // 1 MB
  float* psq  = (float*)(ws + (3u << 20));                         // 1 MB
  float* p2   = (float*)(ws + (4u << 20));                         // 256 KB
  float* scsh = (float*)(ws + (4u << 20) + (256u << 10));          // 4 KB

  wprep_kernel<<<512, 256, 0, stream>>>(weight, Wt);
  gemm_kernel<<<1024, 512, 0, stream>>>(data, neigh, Wt, out, psum, psq);
  reduce1_kernel<<<64, 512, 0, stream>>>(psum, psq, p2);
  reduce2_kernel<<<1, 512, 0, stream>>>(p2, gamma, beta, scsh);
  bn_kernel<<<2048, 512, 0, stream>>>(out, scsh);
}

// Round 7
// 273.660 us; speedup vs baseline: 3.1643x; 1.0360x over previous
//
#include <hip/hip_runtime.h>
#include <hip/hip_bf16.h>

typedef __attribute__((ext_vector_type(8))) short bf16x8;
typedef __attribute__((ext_vector_type(4))) float f32x4;

#define N_OUT 65536
#define CIN   256
#define COUT  512
#define BM    128
#define BN    256
#define BK    32
#define NKS   64    // 2048 / 32 K-steps

__device__ __forceinline__ unsigned short f2bf(float f) {
  union { __hip_bfloat16 h; unsigned short u; } c;
  c.h = __float2bfloat16(f);
  return c.u;
}

__device__ __forceinline__ bf16x8 pack8(f32x4 a, f32x4 b) {
  unsigned short u[8];
  u[0] = f2bf(a.x); u[1] = f2bf(a.y); u[2] = f2bf(a.z); u[3] = f2bf(a.w);
  u[4] = f2bf(b.x); u[5] = f2bf(b.y); u[6] = f2bf(b.z); u[7] = f2bf(b.w);
  return *reinterpret_cast<bf16x8*>(u);
}

__device__ __forceinline__ void gload_lds16f(const float* g, float* l) {
  __builtin_amdgcn_global_load_lds(
      (const __attribute__((address_space(1))) void*)g,
      (__attribute__((address_space(3))) void*)l, 16, 0, 0);
}
__device__ __forceinline__ void gload_lds16u(const unsigned short* g, unsigned short* l) {
  __builtin_amdgcn_global_load_lds(
      (const __attribute__((address_space(1))) void*)g,
      (__attribute__((address_space(3))) void*)l, 16, 0, 0);
}

// --- weight prep: W[k][n] f32 -> Wt bf16 tiled [kb][slot][n][w]:
//     Wt[kb*16384 + s*4096 + n*8 + w] = bf16(W[(kb*32 + s*8 + w)*512 + n])
__global__ void wprep_kernel(const float* __restrict__ W, unsigned short* __restrict__ Wt) {
  int idx = blockIdx.x * blockDim.x + threadIdx.x;
  if (idx >= 64 * 4 * COUT) return;
  int n  = idx & (COUT - 1);
  int s  = (idx >> 9) & 3;
  int kb = idx >> 11;
  unsigned short tmp[8];
#pragma unroll
  for (int w = 0; w < 8; ++w)
    tmp[w] = f2bf(W[(size_t)(kb * 32 + s * 8 + w) * COUT + n]);
  *reinterpret_cast<bf16x8*>(Wt + ((size_t)kb * 16384 + s * 4096 + n * 8)) =
      *reinterpret_cast<bf16x8*>(tmp);
}

// --- main GEMM: 128x256 blocks, 8 waves, wave tile 32x128 (acc=64 regs),
//     all-DMA staging, counted vmcnt; the two n-halves of one m-panel are
//     PAIRED ON ONE XCD (adjacent dispatch) so A's 2nd read is an L2 hit.
__global__ __launch_bounds__(512, 4) void gemm_kernel(
    const float* __restrict__ data,
    const int*   __restrict__ neigh,
    const unsigned short* __restrict__ Wt,
    float* __restrict__ out,
    float* __restrict__ psum,
    float* __restrict__ psq)
{
  __shared__ union {
    struct {
      float          a[2][BM * BK];   // 2 x 16 KB, 16B chunks XOR-swizzled
      unsigned short b[2][BK * BN];   // 2 x 16 KB, linear conflict-free
    } r;                              // 64 KB
    float st[8][BN];                  // 8 KB stats overlay (post-loop)
  } sm;
  __shared__ unsigned int offs[BM * 8];   // 4 KB

  const int tid = threadIdx.x;
  const int l   = tid & 63;
  const int w   = tid >> 6;       // 8 waves
  const int wr  = w >> 1;         // 0..3 (32-row strip)
  const int wc  = w & 1;          // 0..1 (128-col strip)
  const int lg  = l >> 4;
  const int lm  = l & 15;

  // XCD-pairing map (1024 blocks, HW round-robins bid%8 across 8 XCDs):
  // XCD x handles m-panels x*64..x*64+63; consecutive j on one XCD alternate
  // n-halves of the SAME m-panel -> 2nd A read is L2-resident.
  const int bid = blockIdx.x;
  const int xcd = bid & 7;
  const int j   = bid >> 3;             // 0..127 within XCD
  const int mb  = xcd * 64 + (j >> 1);  // 0..511
  const int nh  = j & 1;
  const int n0  = nh * BN;
  const int m0  = mb * BM;
  const int pidx = mb * 2 + nh;         // partials slot

  // neigh -> LDS offset table (float offsets into data)
  for (int e = tid; e < BM * 8; e += 512)
    offs[e] = ((unsigned)neigh[(size_t)m0 * 8 + e]) << 8;
  __syncthreads();

  f32x4 acc[2][8];
#pragma unroll
  for (int i = 0; i < 2; ++i)
#pragma unroll
    for (int jj = 0; jj < 8; ++jj) acc[i][jj] = (f32x4){0.f, 0.f, 0.f, 0.f};

  bf16x8 af[2];

  const int lrow = l >> 3;                              // 0..7
  const int ra   = (w * 16 + lrow) * 8;                 // offs index base, op 0
  const int rb   = (w * 16 + 8 + lrow) * 8;             // op 1
  const int swzf = ((l & 7) ^ lrow) << 2;               // swizzled 16B chunk (rule 21)
  const int q0   = w * 2;                               // B chunk pair
  const unsigned short* bbase =
      Wt + n0 * 8 + (q0 >> 2) * 4096 + (q0 & 3) * 512 + l * 8;

  // A: 2 DMA/wave/step (8 rows each; lane l -> row l>>3, LDS slot l&7,
  //    global chunk (l&7)^(l>>3) so LDS slot s holds chunk s^(row&7))
#define AISSUE(t_, buf_) do { \
    int cn_ = (t_) >> 3; \
    int k0_ = ((t_) & 7) * BK; \
    unsigned o0_ = offs[ra + cn_]; \
    unsigned o1_ = offs[rb + cn_]; \
    gload_lds16f(data + o0_ + k0_ + swzf, &sm.r.a[buf_][(w * 16) * BK]); \
    gload_lds16f(data + o1_ + k0_ + swzf, &sm.r.a[buf_][(w * 16 + 8) * BK]); \
  } while (0)

  // B: 2 DMA/wave/step, linear 512-short chunks
#define BISSUE(t_, buf_) do { \
    const unsigned short* bs_ = bbase + (size_t)(t_) * 16384; \
    gload_lds16u(bs_,       &sm.r.b[buf_][q0 * 512]); \
    gload_lds16u(bs_ + 512, &sm.r.b[buf_][q0 * 512 + 512]); \
  } while (0)

#define COMPUTE(buf_) do { \
    _Pragma("unroll") \
    for (int mi_ = 0; mi_ < 2; ++mi_) { \
      int R_ = wr * 32 + mi_ * 16 + lm; \
      const f32x4* ap_ = reinterpret_cast<const f32x4*>(&sm.r.a[buf_][R_ * BK]); \
      f32x4 x0_ = ap_[(2 * lg)     ^ (R_ & 7)]; \
      f32x4 x1_ = ap_[(2 * lg + 1) ^ (R_ & 7)]; \
      af[mi_] = pack8(x0_, x1_); \
    } \
    _Pragma("unroll") \
    for (int ni_ = 0; ni_ < 8; ++ni_) { \
      bf16x8 bfr_ = *reinterpret_cast<const bf16x8*>( \
          &sm.r.b[buf_][lg * 2048 + (wc * 128 + ni_ * 16 + lm) * 8]); \
      acc[0][ni_] = __builtin_amdgcn_mfma_f32_16x16x32_bf16(af[0], bfr_, acc[0][ni_], 0, 0, 0); \
      acc[1][ni_] = __builtin_amdgcn_mfma_f32_16x16x32_bf16(af[1], bfr_, acc[1][ni_], 0, 0, 0); \
    } \
  } while (0)

  // ---- prologue: steps 0,1 in flight (4 DMA ops/wave each)
  AISSUE(0, 0); BISSUE(0, 0);
  AISSUE(1, 1); BISSUE(1, 1);

#pragma unroll 1
  for (int t = 0; t < NKS; ++t) {
    // counted wait: own 4 step-t ops retired; step t+1's 4 stay in flight
    if (t < NKS - 1) asm volatile("s_waitcnt vmcnt(4)" ::: "memory");
    else             asm volatile("s_waitcnt vmcnt(0)" ::: "memory");
    __builtin_amdgcn_s_barrier();       // all waves: step-t data landed
    asm volatile("" ::: "memory");
    COMPUTE(t & 1);
    asm volatile("" ::: "memory");
    __builtin_amdgcn_s_barrier();       // WAR: reads done before overwrite
    if (t + 2 < NKS) { AISSUE(t + 2, t & 1); BISSUE(t + 2, t & 1); }
  }

  // ---- epilogue 1: raw out (C layout: col = lane&15, row = (lane>>4)*4 + reg)
#pragma unroll
  for (int mi = 0; mi < 2; ++mi) {
#pragma unroll
    for (int r = 0; r < 4; ++r) {
      size_t row = (size_t)(m0 + wr * 32 + mi * 16 + lg * 4 + r);
      float* op = out + row * COUT + n0 + wc * 128 + lm;
#pragma unroll
      for (int ni = 0; ni < 8; ++ni) op[ni * 16] = acc[mi][ni][r];
    }
  }

  // ---- epilogue 2: deterministic per-block column sums/sumsq
  __syncthreads();   // all DMA retired (vmcnt(0)) + LDS reads done
#pragma unroll
  for (int ni = 0; ni < 8; ++ni) {
    float s1 = 0.f, s2 = 0.f;
#pragma unroll
    for (int mi = 0; mi < 2; ++mi)
#pragma unroll
      for (int r = 0; r < 4; ++r) { float v = acc[mi][ni][r]; s1 += v; s2 += v * v; }
    s1 += __shfl_xor(s1, 16, 64); s1 += __shfl_xor(s1, 32, 64);
    s2 += __shfl_xor(s2, 16, 64); s2 += __shfl_xor(s2, 32, 64);
    if (l < 16) {
      sm.st[wr][wc * 128 + ni * 16 + l]     = s1;
      sm.st[4 + wr][wc * 128 + ni * 16 + l] = s2;
    }
  }
  __syncthreads();
  if (tid < 256) {
    float S = sm.st[0][tid] + sm.st[1][tid] + sm.st[2][tid] + sm.st[3][tid];
    psum[(size_t)pidx * BN + tid] = S;
  } else {
    int c = tid - 256;
    float Q = sm.st[4][c] + sm.st[5][c] + sm.st[6][c] + sm.st[7][c];
    psq[(size_t)pidx * BN + c] = Q;
  }
#undef AISSUE
#undef BISSUE
#undef COMPUTE
}

// --- stats reduction, stage 1: 512 m-panels -> 64 partials per column
//     partial layout: psum[(mb*2 + nhalf)*256 + crel], col = nhalf*256 + crel
__global__ void reduce1_kernel(const float* __restrict__ psum, const float* __restrict__ psq,
                               float* __restrict__ p2) {
  int c = threadIdx.x, b = blockIdx.x;
  int h = c >> 8, crel = c & 255;
  float s = 0.f, q = 0.f;
#pragma unroll
  for (int jj = 0; jj < 8; ++jj) {
    size_t pi = (size_t)((b * 8 + jj) * 2 + h);
    s += psum[pi * 256 + crel];
    q += psq [pi * 256 + crel];
  }
  p2[b * 1024 + c] = s;
  p2[b * 1024 + 512 + c] = q;
}

// --- stats reduction, stage 2: mean/var -> per-column scale/shift
__global__ void reduce2_kernel(const float* __restrict__ p2,
                               const float* __restrict__ gamma,
                               const float* __restrict__ beta,
                               float* __restrict__ scsh) {
  int c = threadIdx.x;
  float s = 0.f, q = 0.f;
  for (int b = 0; b < 64; ++b) { s += p2[b * 1024 + c]; q += p2[b * 1024 + 512 + c]; }
  float mean = s * (1.f / 65536.f);
  float var  = q * (1.f / 65536.f) - mean * mean;
  float rs   = rsqrtf(var + 1e-5f);
  float sc   = gamma[c] * rs;
  scsh[c] = sc;
  scsh[COUT + c] = beta[c] - mean * sc;   // conv bias cancels in BN
}

// --- apply BN in-place
__global__ void bn_kernel(float* __restrict__ out, const float* __restrict__ scsh) {
  __shared__ float sc[COUT], sh[COUT];
  int t = threadIdx.x;
  sc[t] = scsh[t];
  sh[t] = scsh[COUT + t];
  __syncthreads();
  f32x4* o4 = reinterpret_cast<f32x4*>(out);
  const size_t total  = (size_t)N_OUT * COUT / 4;
  const size_t stride = (size_t)gridDim.x * blockDim.x;
  for (size_t i = (size_t)blockIdx.x * blockDim.x + t; i < total; i += stride) {
    f32x4 v = o4[i];
    int c = ((int)(i & 127)) * 4;
    v.x = v.x * sc[c]     + sh[c];
    v.y = v.y * sc[c + 1] + sh[c + 1];
    v.z = v.z * sc[c + 2] + sh[c + 2];
    v.w = v.w * sc[c + 3] + sh[c + 3];
    o4[i] = v;
  }
}

extern "C" void kernel_launch(void* const* d_in, const int* in_sizes, int n_in,
                              void* d_out, int out_size, void* d_ws, size_t ws_size,
                              hipStream_t stream) {
  const float* data   = (const float*)d_in[0];
  const float* weight = (const float*)d_in[1];
  const float* gamma  = (const float*)d_in[3];
  const float* beta   = (const float*)d_in[4];
  const int*   neigh  = (const int*)d_in[5];
  float* out = (float*)d_out;

  char* ws = (char*)d_ws;
  unsigned short* Wt = (unsigned short*)ws;                        // 2 MB
  float* psum = (float*)(ws + (2u << 20));                         // 1 MB
  float* psq  = (float*)(ws + (3u << 20));                         // 1 MB
  float* p2   = (float*)(ws + (4u << 20));                         // 256 KB
  float* scsh = (float*)(ws + (4u << 20) + (256u << 10));          // 4 KB

  wprep_kernel<<<512, 256, 0, stream>>>(weight, Wt);
  gemm_kernel<<<1024, 512, 0, stream>>>(data, neigh, Wt, out, psum, psq);
  reduce1_kernel<<<64, 512, 0, stream>>>(psum, psq, p2);
  reduce2_kernel<<<1, 512, 0, stream>>>(p2, gamma, beta, scsh);
  bn_kernel<<<2048, 512, 0, stream>>>(out, scsh);
}